// Round 12
// baseline (34.719 us; speedup 1.0000x reference)
//
#include <hip/hip_runtime.h>
#include <hip/hip_bf16.h>

// RedistributionNetwork: 128 sequential tridiagonal layers on [256,1024] f32 state.
// Pipeline:
//  (A) gather_compose8: gather 8 layers' tridiags (one dwordx4 per row) into LDS,
//      compose the 8-layer product -> 17-diagonal f32 band[16][17][1024] (1.06 MB).
//  (B) propagate17: 16 seventeen-diagonal stencil steps. 512 thr (8 waves,
//      2/SIMD), 2 rows/lane, halo via 16 shuffles + windowed LDS edge patches
//      (compile-time register indices), parity LDS double-buffer, lgkmcnt-only
//      barrier per step. Rationale: measured per-step cost is latency/DS-bound
//      (~1070cy at R11) and sub-linear in work -> fewer fatter steps win.

#define NXL 128
#define NYP 1024
#define NB  256
#define NG  16     // groups of 8 layers
#define ND  17     // diagonals of the composed operator
#define SL  64     // composed rows per block
#define HRW 84     // staged rows per layer per block (SL + 9 halo each side + pad)

struct __attribute__((packed, aligned(4))) f4u { float x, y, z, w; };

// ---------------- kernel A: gather + depth-8 compose ----------------
// band[g][d][i] = M_g[i, i+d-8], M_g = W[8g+7]···W[8g]; exact 0 out of matrix.
__global__ __launch_bounds__(256) void gather_compose8(const float* __restrict__ W,
                                                       float* __restrict__ band) {
    __shared__ float ta[8][3][HRW];   // [layer][a,b,c][local row]
    const int blk = blockIdx.x;       // 0..255
    const int g   = blk >> 4;
    const int sl  = blk & 15;
    const int i0  = sl * SL;
    const int tid = threadIdx.x;

#pragma unroll
    for (int gi = tid; gi < 8 * HRW; gi += 256) {
        int ly = gi / HRW;
        int rr = gi - ly * HRW;
        int i  = i0 - 9 + rr;         // rows i0-9 .. i0+74 (need i0-9..i0+72)
        float a = 0.0f, b = 0.0f, c = 0.0f;
        if ((unsigned)i < NYP) {
            size_t base = ((size_t)(8 * g + ly) << 20) + (size_t)i * (NYP + 1);
            const float* lp = W + base + ((i == 0) ? 0 : (i == NYP - 1) ? -3 : -1);
            f4u v = *reinterpret_cast<const f4u*>(lp);
            if (i == 0)            { a = 0.0f; b = v.x; c = v.y; }
            else if (i == NYP - 1) { a = v.z;  b = v.w; c = 0.0f; }
            else                   { a = v.x;  b = v.y; c = v.z; }
        }
        ta[ly][0][rr] = a;
        ta[ly][1][rr] = b;
        ta[ly][2][rr] = c;
    }
    __syncthreads();

    if (tid < SL) {
        const int i  = i0 + tid;
        const int li = tid + 9;       // LDS slot of row i; col i+o -> slot li+o
        // p[9+o] = row-vector coefficient at column i+o
        float p[19], r[19];
#pragma unroll
        for (int k = 0; k < 19; ++k) { p[k] = 0.0f; r[k] = 0.0f; }
        p[8] = ta[7][0][li]; p[9] = ta[7][1][li]; p[10] = ta[7][2][li];  // e_i^T W7

        // p := p · W_ly  for ly = 6..0; (p·W)[c] = p[c+1]a(c+1)+p[c]b(c)+p[c-1]c(c-1)
#pragma unroll
        for (int k = 1; k <= 7; ++k) {
            const int ly = 7 - k;
#pragma unroll
            for (int o = -8; o <= 8; ++o) {
                if (o < -(k + 1) || o > (k + 1)) continue;   // compile-time prune
                r[9 + o] = fmaf(p[10 + o], ta[ly][0][li + o + 1],
                           fmaf(p[9 + o],  ta[ly][1][li + o],
                                p[8 + o] * ta[ly][2][li + o - 1]));
            }
#pragma unroll
            for (int kk = 0; kk < 19; ++kk) p[kk] = r[kk];
        }

        float* dst = band + ((size_t)g * ND << 10) + i;
#pragma unroll
        for (int d = 0; d < ND; ++d)
            dst[(size_t)d << 10] = p[d + 1];   // offset d-8 lives at p[9+(d-8)]
    }
}

// ---------------- kernel B: 17-diagonal propagation, 16 steps ----------------
__device__ __forceinline__ void ldsbar() {
    asm volatile("s_waitcnt lgkmcnt(0)" ::: "memory");
    __builtin_amdgcn_s_barrier();
}

__device__ __forceinline__ void loadw(const float* __restrict__ band, int sIdx,
                                      int R, float2 (&q)[ND]) {
    const float* base = band + (((size_t)sIdx * ND) << 10) + R;
#pragma unroll
    for (int d = 0; d < ND; ++d)
        q[d] = *reinterpret_cast<const float2*>(base + ((size_t)d << 10));
}

// edge[par][w][16]: boundary w holds rows 128w-8 .. 128w+7.
// Each edge lane reads an 8-float window CENTERED ON ITS OWN ROWS, so the
// patch selects below use fixed register indices (no runtime reg indexing).
__device__ __forceinline__ void readhalo(const float (*e)[16], int w, int l,
                                         float (&gl)[8], float (&gr)[8]) {
#pragma unroll
    for (int j = 0; j < 8; ++j) { gl[j] = 0.0f; gr[j] = 0.0f; }
    if (l < 4) {                      // rows R-8..R-1, window starts at slot 2l
        const float* p = &e[w][2 * l];
#pragma unroll
        for (int j = 0; j < 8; ++j) gl[j] = p[j];
    }
    if (l >= 60) {                    // rows R+2..R+9, window starts at 2l-118
        const float* p = &e[w + 1][2 * l - 118];
#pragma unroll
        for (int j = 0; j < 8; ++j) gr[j] = p[j];
    }
}

__device__ __forceinline__ void stepY(float& h0, float& h1, const float2 (&q)[ND],
                                      float (&gl)[8], float (&gr)[8],
                                      float (*nxt)[16], int w, int l) {
    // 16 static shuffles (rows R-8..R+9 via lane +-1..4)
    float s0u1 = __shfl_up(h0, 1),   s1u1 = __shfl_up(h1, 1);
    float s0u2 = __shfl_up(h0, 2),   s1u2 = __shfl_up(h1, 2);
    float s0u3 = __shfl_up(h0, 3),   s1u3 = __shfl_up(h1, 3);
    float s0u4 = __shfl_up(h0, 4),   s1u4 = __shfl_up(h1, 4);
    float s0d1 = __shfl_down(h0, 1), s1d1 = __shfl_down(h1, 1);
    float s0d2 = __shfl_down(h0, 2), s1d2 = __shfl_down(h1, 2);
    float s0d3 = __shfl_down(h0, 3), s1d3 = __shfl_down(h1, 3);
    float s0d4 = __shfl_down(h0, 4), s1d4 = __shfl_down(h1, 4);
    // wave-edge patches (fixed gl/gr indices; out-of-matrix killed by exact-0 coefs)
    s0u1 = (l < 1) ? gl[6] : s0u1;   s1u1 = (l < 1) ? gl[7] : s1u1;
    s0u2 = (l < 2) ? gl[4] : s0u2;   s1u2 = (l < 2) ? gl[5] : s1u2;
    s0u3 = (l < 3) ? gl[2] : s0u3;   s1u3 = (l < 3) ? gl[3] : s1u3;
    s0u4 = (l < 4) ? gl[0] : s0u4;   s1u4 = (l < 4) ? gl[1] : s1u4;
    s0d1 = (l > 62) ? gr[0] : s0d1;  s1d1 = (l > 62) ? gr[1] : s1d1;
    s0d2 = (l > 61) ? gr[2] : s0d2;  s1d2 = (l > 61) ? gr[3] : s1d2;
    s0d3 = (l > 60) ? gr[4] : s0d3;  s1d3 = (l > 60) ? gr[5] : s1d3;
    s0d4 = (l > 59) ? gr[6] : s0d4;  s1d4 = (l > 59) ? gr[7] : s1d4;

    // row R: cols R-8..R+8, weights q[d].x ; two chains for shorter dep depth
    float a0 =            q[0].x * s0u4;
    a0 = fmaf(q[1].x,  s1u4, a0);
    a0 = fmaf(q[2].x,  s0u3, a0);
    a0 = fmaf(q[3].x,  s1u3, a0);
    a0 = fmaf(q[4].x,  s0u2, a0);
    a0 = fmaf(q[5].x,  s1u2, a0);
    a0 = fmaf(q[6].x,  s0u1, a0);
    a0 = fmaf(q[7].x,  s1u1, a0);
    float b0 =            q[8].x * h0;
    b0 = fmaf(q[9].x,  h1,   b0);
    b0 = fmaf(q[10].x, s0d1, b0);
    b0 = fmaf(q[11].x, s1d1, b0);
    b0 = fmaf(q[12].x, s0d2, b0);
    b0 = fmaf(q[13].x, s1d2, b0);
    b0 = fmaf(q[14].x, s0d3, b0);
    b0 = fmaf(q[15].x, s1d3, b0);
    b0 = fmaf(q[16].x, s0d4, b0);
    float n0 = a0 + b0;
    // row R+1: cols R-7..R+9, weights q[d].y
    float a1 =            q[0].y * s1u4;
    a1 = fmaf(q[1].y,  s0u3, a1);
    a1 = fmaf(q[2].y,  s1u3, a1);
    a1 = fmaf(q[3].y,  s0u2, a1);
    a1 = fmaf(q[4].y,  s1u2, a1);
    a1 = fmaf(q[5].y,  s0u1, a1);
    a1 = fmaf(q[6].y,  s1u1, a1);
    a1 = fmaf(q[7].y,  h0,   a1);
    float b1 =            q[8].y * h1;
    b1 = fmaf(q[9].y,  s0d1, b1);
    b1 = fmaf(q[10].y, s1d1, b1);
    b1 = fmaf(q[11].y, s0d2, b1);
    b1 = fmaf(q[12].y, s1d2, b1);
    b1 = fmaf(q[13].y, s0d3, b1);
    b1 = fmaf(q[14].y, s1d3, b1);
    b1 = fmaf(q[15].y, s0d4, b1);
    b1 = fmaf(q[16].y, s1d4, b1);
    float n1 = a1 + b1;

    h0 = n0; h1 = n1;
    // publish new edge rows for next step (other parity buffer)
    if (l < 4)   { nxt[w][8 + 2 * l] = h0;           nxt[w][9 + 2 * l] = h1; }
    if (l >= 60) { nxt[w + 1][2 * (l - 60)] = h0;    nxt[w + 1][2 * (l - 60) + 1] = h1; }
    ldsbar();                    // LDS-scope only; weight prefetch stays in flight
    readhalo(nxt, w, l, gl, gr); // issue next step's halo reads now
}

__global__ __launch_bounds__(512) void propagate17(const float* __restrict__ x,
                                                   const float* __restrict__ band,
                                                   float* __restrict__ out) {
    __shared__ float edge[2][9][16];
    const int b = blockIdx.x;
    const int t = threadIdx.x;
    const int w = t >> 6;
    const int l = t & 63;
    const int R = t << 1;        // rows R, R+1

    float h0, h1;
    {
        float2 v = *reinterpret_cast<const float2*>(x + (size_t)b * NYP + R);
        h0 = v.x; h1 = v.y;
    }
    // zero the never-published corner windows (rows <0 and >=1024); their values
    // are multiplied by exact-0 coefficients but must not be NaN garbage
    if (t < 8) {
        edge[0][0][t] = 0.0f; edge[1][0][t] = 0.0f;
        edge[0][8][8 + t] = 0.0f; edge[1][8][8 + t] = 0.0f;
    }

    float2 qa[ND], qb[ND];
    loadw(band, 0, R, qa);

    // prologue: publish step-0 edge rows into parity 0
    if (l < 4)   { edge[0][w][8 + 2 * l] = h0;        edge[0][w][9 + 2 * l] = h1; }
    if (l >= 60) { edge[0][w + 1][2 * (l - 60)] = h0; edge[0][w + 1][2 * (l - 60) + 1] = h1; }
    ldsbar();
    float gl[8], gr[8];
    readhalo(edge[0], w, l, gl, gr);

#pragma unroll 1
    for (int s = 0; s < NG; s += 2) {
        loadw(band, (s + 1 < NG) ? s + 1 : NG - 1, R, qb);
        stepY(h0, h1, qa, gl, gr, edge[1], w, l);   // writes parity 1
        loadw(band, (s + 2 < NG) ? s + 2 : NG - 1, R, qa);
        stepY(h0, h1, qb, gl, gr, edge[0], w, l);   // writes parity 0
    }

    *reinterpret_cast<float2*>(out + (size_t)b * NYP + R) = make_float2(h0, h1);
}

// ---------------- fallback: direct tridiag sweep from W (ws too small) ----------------
__device__ __forceinline__ float gAw(const float* __restrict__ Wl, int r) {
    return (r >= 1 && r < NYP) ? Wl[(size_t)r * NYP + (r - 1)] : 0.0f;
}
__device__ __forceinline__ float gBw(const float* __restrict__ Wl, int r) {
    return ((unsigned)r < NYP) ? Wl[(size_t)r * NYP + r] : 0.0f;
}
__device__ __forceinline__ float gCw(const float* __restrict__ Wl, int r) {
    return (r >= 0 && r < NYP - 1) ? Wl[(size_t)r * NYP + (r + 1)] : 0.0f;
}

__global__ __launch_bounds__(64) void propagate_direct(const float* __restrict__ x,
                                                       const float* __restrict__ W,
                                                       float* __restrict__ out) {
    const int b    = blockIdx.x;
    const int lane = threadIdx.x & 63;
    const int r0   = lane * 16;

    float h[16];
    const float4* xb = reinterpret_cast<const float4*>(x + (size_t)b * NYP + r0);
#pragma unroll
    for (int t = 0; t < 4; ++t) {
        float4 v = xb[t];
        h[4 * t + 0] = v.x; h[4 * t + 1] = v.y;
        h[4 * t + 2] = v.z; h[4 * t + 3] = v.w;
    }

#pragma unroll 1
    for (int ll = 0; ll < NXL; ++ll) {
        const float* Wl = W + ((size_t)ll << 20);
        float a[16], bb[16], c[16];
#pragma unroll
        for (int k = 0; k < 16; ++k) {
            int i = r0 + k;
            a[k] = gAw(Wl, i); bb[k] = gBw(Wl, i); c[k] = gCw(Wl, i);
        }
        float left  = __shfl_up(h[15], 1);
        float right = __shfl_down(h[0], 1);
        float carry = left;
        float n[16];
#pragma unroll
        for (int j = 0; j < 16; ++j) {
            float hp = (j == 15) ? right : h[j + 1];
            n[j] = fmaf(a[j], carry, fmaf(bb[j], h[j], c[j] * hp));
            carry = h[j];
        }
#pragma unroll
        for (int j = 0; j < 16; ++j) h[j] = n[j];
    }

    float4* ob = reinterpret_cast<float4*>(out + (size_t)b * NYP + r0);
#pragma unroll
    for (int t = 0; t < 4; ++t)
        ob[t] = make_float4(h[4 * t + 0], h[4 * t + 1], h[4 * t + 2], h[4 * t + 3]);
}

extern "C" void kernel_launch(void* const* d_in, const int* in_sizes, int n_in,
                              void* d_out, int out_size, void* d_ws, size_t ws_size,
                              hipStream_t stream) {
    const float* x = (const float*)d_in[0];   // [256,1024] f32
    const float* W = (const float*)d_in[1];   // [128,1024,1024] f32
    float* out = (float*)d_out;               // [256,1024] f32

    const size_t bandBytes = (size_t)NG * ND * NYP * sizeof(float);  // 1.06 MB
    if (ws_size >= bandBytes) {
        float* band = (float*)d_ws;
        gather_compose8<<<256, 256, 0, stream>>>(W, band);
        propagate17<<<NB, 512, 0, stream>>>(x, band, out);
    } else {
        propagate_direct<<<NB, 64, 0, stream>>>(x, W, out);
    }
}